// Round 7
// baseline (173.350 us; speedup 1.0000x reference)
//
#include <hip/hip_runtime.h>
#include <hip/hip_bf16.h>
#include <stdint.h>

#define B_SZ 8192
#define D_SZ 512
#define U_SZ 512
#define M_SZ 16
#define K_SZ 64

typedef short bf16x8 __attribute__((ext_vector_type(8)));
typedef float f32x4 __attribute__((ext_vector_type(4)));

__device__ __forceinline__ unsigned short f2bf(float f) {
  union { float f; unsigned u; } v; v.f = f;
  unsigned r = v.u + 0x7fffu + ((v.u >> 16) & 1u);
  return (unsigned short)(r >> 16);
}

// =====================================================================
// prep1: role-split single launch. ALL outputs are fragment-linear bf16.
//  [0,2048):    kernels [M][D][U] f32 -> kbf [m][ut][kt][j][h][lane][8]
//  [2048,2056): key_kernel [D][K]     -> wkbf [kt][j][h][lane][8]
//  [2056,2568): x [B][D]              -> xbf [bt][kt][i][h][lane][8]
// ROUND-7: role T phase-2 remapped so each WAVE writes a contiguous 1KB
// kbf chunk (was 64 scattered 16B writes per wave). Same (j,lane,e)
// bijection, only the thread assignment changed: j = t>>6, lane = t&63.
// =====================================================================
__global__ __launch_bounds__(256) void prep1(
    const float* __restrict__ x, const float* __restrict__ key_kernel,
    const float* __restrict__ kernels, unsigned short* __restrict__ xbf,
    unsigned short* __restrict__ kbf, unsigned short* __restrict__ wkbf) {
  __shared__ float tf[32][65];
  __shared__ unsigned short sx[16][520];
  int bid = blockIdx.x;
  int t = threadIdx.x;

  if (bid < 2048) {
    // ---- role T: kernels -> kbf (frag-linear B operand) ----
    int m = bid >> 7;
    int rem = bid & 127;
    int a = (rem >> 3) & 15;  // d-tile (32 d's)
    int ut = rem & 7;         // u-tile (64 u's)
    int d0 = a * 32, u0 = ut * 64;
    {
      int dr = t >> 4, uc = t & 15;
      const float* src = kernels + ((size_t)m * D_SZ + d0 + dr) * U_SZ + u0 + uc * 4;
      float4 aa = *(const float4*)src;
      float4 bb = *(const float4*)(src + (size_t)16 * U_SZ);
      tf[dr][uc * 4 + 0] = aa.x; tf[dr][uc * 4 + 1] = aa.y;
      tf[dr][uc * 4 + 2] = aa.z; tf[dr][uc * 4 + 3] = aa.w;
      tf[dr + 16][uc * 4 + 0] = bb.x; tf[dr + 16][uc * 4 + 1] = bb.y;
      tf[dr + 16][uc * 4 + 2] = bb.z; tf[dr + 16][uc * 4 + 3] = bb.w;
    }
    __syncthreads();
    {
      int j = t >> 6;            // frag col-block 0..3 (== wave id)
      int lp = t & 63;           // frag lane 0..63
      int dc = lp >> 4, lane16 = lp & 15;
      int kt = a >> 1, h = a & 1;
      int ur = j * 16 + lane16;  // u-row 0..63
      unsigned short* dst = kbf +
          (((((size_t)m * 8 + ut) * 8 + kt) * 4 + j) * 2 + h) * 512 +
          (size_t)lp * 8;
      ushort4 lo, hi;
      lo.x = f2bf(tf[dc * 8 + 0][ur]); lo.y = f2bf(tf[dc * 8 + 1][ur]);
      lo.z = f2bf(tf[dc * 8 + 2][ur]); lo.w = f2bf(tf[dc * 8 + 3][ur]);
      hi.x = f2bf(tf[dc * 8 + 4][ur]); hi.y = f2bf(tf[dc * 8 + 5][ur]);
      hi.z = f2bf(tf[dc * 8 + 6][ur]); hi.w = f2bf(tf[dc * 8 + 7][ur]);
      *(ushort4*)dst = lo;
      *(ushort4*)(dst + 4) = hi;
    }
    return;
  }

  if (bid < 2056) {
    // ---- role W: key_kernel -> wkbf ----
    int kt = bid - 2048;
#pragma unroll
    for (int rep = 0; rep < 2; ++rep) {
      int c = rep * 256 + t;
      int j = c >> 7, h = (c >> 6) & 1, quad = (c >> 4) & 3, ln = c & 15;
      int dd = kt * 64 + h * 32 + quad * 8;
      int u = j * 16 + ln;
      unsigned short v[8];
#pragma unroll
      for (int e = 0; e < 8; ++e)
        v[e] = f2bf(key_kernel[(size_t)(dd + e) * K_SZ + u]);
      unsigned short* dst =
          wkbf + ((size_t)((kt * 4 + j) * 2 + h) * 64 + quad * 16 + ln) * 8;
#pragma unroll
      for (int e = 0; e < 8; ++e) dst[e] = v[e];
    }
    return;
  }

  // ---- role X (v2): x -> xbf via LDS transpose, coalesced reads ----
  {
    int xb0 = bid - 2056;            // 0..511, 16 rows each
    int btx = xb0 >> 3, i = xb0 & 7;
    int b0 = xb0 * 16;
#pragma unroll
    for (int rep = 0; rep < 8; ++rep) {
      int idx = rep * 256 + t;       // 0..2047
      int row = idx >> 7;            // 0..15
      int c4 = (idx & 127) * 4;      // 0..508
      float4 v = *(const float4*)(x + (size_t)(b0 + row) * D_SZ + c4);
      ushort4 o;
      o.x = f2bf(v.x); o.y = f2bf(v.y); o.z = f2bf(v.z); o.w = f2bf(v.w);
      *(ushort4*)(&sx[row][c4]) = o;
    }
    __syncthreads();
    int w = t >> 6, l = t & 63;
    int ln = l & 15, quad = l >> 4;
#pragma unroll
    for (int rep = 0; rep < 4; ++rep) {
      int c = w * 4 + rep;           // chunk 0..15 = (kt,h)
      int kt = c >> 1, h = c & 1;
      const unsigned short* srcp = &sx[ln][kt * 64 + h * 32 + quad * 8];
      ushort4 lo = *(const ushort4*)(srcp);
      ushort4 hi = *(const ushort4*)(srcp + 4);
      unsigned short* dst =
          xbf + ((((size_t)btx * 8 + kt) * 8 + i) * 2 + h) * 512 + (size_t)l * 8;
      *(ushort4*)dst = lo;
      *(ushort4*)(dst + 4) = hi;
    }
  }
}

// =====================================================================
// prep2: keyv = xb @ Wk + bias (MFMA, frags direct from global), then sim.
// =====================================================================
__global__ __launch_bounds__(256) void prep2(
    const unsigned short* __restrict__ xbf, const unsigned short* __restrict__ wkbf,
    const float* __restrict__ key_bias, const float* __restrict__ keys_map,
    float* __restrict__ simT) {
  __shared__ float kv[64][68];
  __shared__ float sKM[16][64];
  int t = threadIdx.x, w = t >> 6, l = t & 63;
  int blk = blockIdx.x;
  int b0 = blk * 64, bt = blk >> 1, ibase = (blk & 1) * 4;
  int lane16 = l & 15, quad = l >> 4;

  ((float4*)sKM)[t] = ((const float4*)keys_map)[t];

  f32x4 acc[4];
#pragma unroll
  for (int j = 0; j < 4; ++j) acc[j] = (f32x4){0.f, 0.f, 0.f, 0.f};

  for (int kt = 0; kt < 8; ++kt) {
    bf16x8 af[2];
#pragma unroll
    for (int h = 0; h < 2; ++h)
      af[h] = *(const bf16x8*)(xbf +
                               ((((size_t)bt * 8 + kt) * 8 + ibase + w) * 2 + h) * 512 +
                               (size_t)l * 8);
#pragma unroll
    for (int j = 0; j < 4; ++j) {
      bf16x8 b0f = *(const bf16x8*)(wkbf + ((size_t)((kt * 4 + j) * 2 + 0) * 64 + l) * 8);
      bf16x8 b1f = *(const bf16x8*)(wkbf + ((size_t)((kt * 4 + j) * 2 + 1) * 64 + l) * 8);
      acc[j] = __builtin_amdgcn_mfma_f32_16x16x32_bf16(af[0], b0f, acc[j], 0, 0, 0);
      acc[j] = __builtin_amdgcn_mfma_f32_16x16x32_bf16(af[1], b1f, acc[j], 0, 0, 0);
    }
  }
#pragma unroll
  for (int j = 0; j < 4; ++j) {
    float bc = key_bias[j * 16 + lane16];
#pragma unroll
    for (int r = 0; r < 4; ++r)
      kv[w * 16 + quad * 4 + r][j * 16 + lane16] = acc[j][r] + bc;
  }
  __syncthreads();

  int row = t >> 2, mg = (t & 3) * 4;
  float d2[4] = {0.f, 0.f, 0.f, 0.f};
#pragma unroll 8
  for (int k = 0; k < 64; ++k) {
    float kvv = kv[row][k];
#pragma unroll
    for (int q = 0; q < 4; ++q) {
      float df = kvv - sKM[mg + q][k];
      d2[q] += df * df;
    }
  }
#pragma unroll
  for (int q = 0; q < 4; ++q)
    simT[(size_t)(mg + q) * B_SZ + b0 + row] = 1.0f / (sqrtf(d2[q]) + 1.0f);
}

// =====================================================================
// poly_gemm v8: out[b,u] = (1/16) sum_m sim[b,m]*(x@kernels_m + biases_m)
//
// ROUND-7: R6 hit the LDS-read wall: B-bytes-from-LDS per MFMA = 1024/i
// (i = A-frags/wave). R6 i=2 -> 512B/MFMA -> ~41us LDS duty of 80.7us.
// This version: i=4 via MODE-SPLIT, keeping R6's proven 2 waves/SIMD.
//  - 256 blocks (32 bt x 8 ut XCD-pinned), 512 thr = 8 waves =
//    4 row-groups (rg=w>>1, 64 rows, facc[4][4]) x 2 mode-halves (w&1).
//  - per iter (64 iters = 8kt x 8mi): TWO slices staged (one per half),
//    each wave DMAs 2KB of its half's slice (2x global_load_lds 1KB).
//  - ring: 4 slots x 2 halves x 8KB = 64KB; lookahead 2. Race-safe:
//    slot of slice s+2 was consumed at iter s-2; those ds_reads are
//    lgkm-complete (MFMA reg dependency) before barrier(s-1); the stage
//    DMA is issued after barrier(s-1). (R5's proven ring geometry.)
//  - vmcnt ledger (per wave, 2 DMA/iter, af=8 loads at mi==0,kt<7):
//    mi in {0,1,2} && kt<7 -> vmcnt(12); else vmcnt(4). Never 0 in-loop.
//  - LDS bfr traffic halves: 8 waves x 8KB x 64 iters = 4.1MB/CU
//    (~20us duty); barriers halve (64). MFMA floor 8.3us/CU.
//  - epilogue: drain + mode-half combine via 69.6KB sRed overlay.
// =====================================================================
#define GLL(src_, dst_)                                                        \
  __builtin_amdgcn_global_load_lds(                                            \
      (const __attribute__((address_space(1))) unsigned int*)(src_),           \
      (__attribute__((address_space(3))) unsigned int*)(dst_), 16, 0, 0)

#define STAGE(mi_, kt_, slot_)                                                 \
  {                                                                            \
    const unsigned short* _src = kbf_l +                                       \
        (((size_t)((w & 1) * 8 + (mi_)) * 8 + ut) * 8 + (kt_)) * 4096 +        \
        (w >> 1) * 1024;                                                       \
    unsigned short* _dst =                                                     \
        Bbuf + ((slot_) * 2 + (w & 1)) * 4096 + (w >> 1) * 1024;               \
    GLL(_src, _dst);                                                           \
    GLL(_src + 512, _dst + 512);                                               \
  }

#define LOAD_AF(dst_, kt_)                                                     \
  _Pragma("unroll") for (int ii = 0; ii < 4; ++ii)                             \
      _Pragma("unroll") for (int h = 0; h < 2; ++h) {                          \
    int g_ = bt * 16 + rg * 4 + ii;                                            \
    dst_[ii][h] = *(const bf16x8*)(                                            \
        xbf + ((((size_t)(g_ >> 3) * 8 + (kt_)) * 8 + (g_ & 7)) * 2 + h) *     \
                  512 +                                                        \
              (size_t)l * 8);                                                  \
  }

__global__ __launch_bounds__(512, 2) void poly_gemm(
    const unsigned short* __restrict__ xbf,  // A frag-linear
    const unsigned short* __restrict__ kbf,  // B frag-linear
    const float* __restrict__ simT,          // [M][B]
    const float* __restrict__ biases,        // [M][U] f32
    float* __restrict__ out) {               // [B][U]
  // LDS: [0,64K) 4slot x 2half x 8KB | [64K,80K) sSim[16][256] |
  // [80K,84K) sBias[16][64]. Epilogue overlays sRed (256x68 f32).
  __shared__ __align__(16) char smem[86016];

  int t = threadIdx.x, w = t >> 6, l = t & 63;
  int bid = blockIdx.x;
  int ut = bid & 7, bt = bid >> 3;  // ut: XCD-pinned kbf slice
  int b0 = bt * 256, u0 = ut * 64;
  int rg = w >> 1, half = w & 1;
  int lane16 = l & 15, quad = l >> 4;

  unsigned short* Bbuf = (unsigned short*)smem;
  float* sSim = (float*)(smem + 65536);
  float* sBias = (float*)(smem + 81920);

  // ---- stage sim [16][256] and bias [16][64] once (512 threads) ----
  {
    int m = t >> 5, c = (t & 31) * 8;
    const float* src = simT + (size_t)m * B_SZ + b0 + c;
    float4* dst = (float4*)(sSim + m * 256 + c);
    dst[0] = ((const float4*)src)[0];
    dst[1] = ((const float4*)src)[1];
    int bi = t * 2;  // 0..1022
    *(float2*)(sBias + bi) =
        *(const float2*)(biases + (size_t)(bi >> 6) * U_SZ + u0 + (bi & 63));
  }

  const unsigned short* kbf_l = kbf + (size_t)l * 8;

  bf16x8 afc[4][2], afn[4][2];

  // prologue: stage slices s=0,1 (both halves), load af(kt0), drain.
  STAGE(0, 0, 0);
  STAGE(1, 0, 1);
  LOAD_AF(afc, 0);
  asm volatile("s_waitcnt vmcnt(0)" ::: "memory");
  __syncthreads();

  f32x4 facc[4][4];
#pragma unroll
  for (int i = 0; i < 4; ++i)
#pragma unroll
    for (int j = 0; j < 4; ++j) facc[i][j] = (f32x4){0.f, 0.f, 0.f, 0.f};

#pragma unroll 1
  for (int kt = 0; kt < 8; ++kt) {
#pragma unroll
    for (int mi = 0; mi < 8; ++mi) {
      const int s = kt * 8 + mi;
      const int mode = half * 8 + mi;
      // stage slice s+2 for this wave's half
      {
        int mi2 = (mi + 2) & 7;
        int kt2 = (mi >= 6) ? ((kt + 1) & 7) : kt;
        STAGE(mi2, kt2, (s + 2) & 3);
      }
      if (mi == 0 && kt < 7) { LOAD_AF(afn, kt + 1); }
      // counted waits per the ledger (never 0 in-loop)
      if (mi < 3 && kt < 7)
        asm volatile("s_waitcnt vmcnt(12)" ::: "memory");
      else
        asm volatile("s_waitcnt vmcnt(4)" ::: "memory");
      asm volatile("s_barrier" ::: "memory");

      const unsigned short* lb = Bbuf + ((s & 3) * 2 + half) * 4096;
      bf16x8 bfr[4][2];
#pragma unroll
      for (int j = 0; j < 4; ++j)
#pragma unroll
        for (int h = 0; h < 2; ++h)
          bfr[j][h] = *(const bf16x8*)(lb + (j * 2 + h) * 512 + (size_t)l * 8);

      f32x4 sv[4];
#pragma unroll
      for (int i = 0; i < 4; ++i)
        sv[i] = *(const f32x4*)(sSim + mode * 256 + rg * 64 + i * 16 +
                                quad * 4);

#pragma unroll
      for (int i = 0; i < 4; ++i)
#pragma unroll
        for (int j = 0; j < 4; ++j) {
          f32x4 p = __builtin_amdgcn_mfma_f32_16x16x32_bf16(
              afc[i][0], bfr[j][0], (f32x4){0.f, 0.f, 0.f, 0.f}, 0, 0, 0);
          p = __builtin_amdgcn_mfma_f32_16x16x32_bf16(afc[i][1], bfr[j][1], p,
                                                      0, 0, 0);
#pragma unroll
          for (int r = 0; r < 4; ++r) facc[i][j][r] += sv[i][r] * p[r];
        }

      if (kt == 0) {  // sim-weighted bias, once per mode
        float bbv[4];
#pragma unroll
        for (int j = 0; j < 4; ++j)
          bbv[j] = sBias[mode * 64 + j * 16 + lane16];
#pragma unroll
        for (int i = 0; i < 4; ++i)
#pragma unroll
          for (int j = 0; j < 4; ++j)
#pragma unroll
            for (int r = 0; r < 4; ++r) facc[i][j][r] += sv[i][r] * bbv[j];
      }
    }
    if (kt < 7) {
#pragma unroll
      for (int ii = 0; ii < 4; ++ii)
#pragma unroll
        for (int h = 0; h < 2; ++h) afc[ii][h] = afn[ii][h];
    }
  }

  // epilogue: drain wrap-stage DMA, then mode-half combine via sRed.
  asm volatile("s_waitcnt vmcnt(0)" ::: "memory");
  __syncthreads();
  float* sRed = (float*)smem;  // [256][68] overlay on Bbuf+sSim
  if (half == 1) {
#pragma unroll
    for (int i = 0; i < 4; ++i)
#pragma unroll
      for (int r = 0; r < 4; ++r)
#pragma unroll
        for (int j = 0; j < 4; ++j)
          sRed[(rg * 64 + i * 16 + quad * 4 + r) * 68 + j * 16 + lane16] =
              facc[i][j][r];
  }
  __syncthreads();
  if (half == 0) {
#pragma unroll
    for (int i = 0; i < 4; ++i)
#pragma unroll
      for (int r = 0; r < 4; ++r) {
        int row = b0 + rg * 64 + i * 16 + quad * 4 + r;
        float* orow = out + (size_t)row * U_SZ + u0;
#pragma unroll
        for (int j = 0; j < 4; ++j)
          orow[j * 16 + lane16] =
              (facc[i][j][r] +
               sRed[(rg * 64 + i * 16 + quad * 4 + r) * 68 + j * 16 + lane16]) *
              0.0625f;
      }
  }
}

extern "C" void kernel_launch(void* const* d_in, const int* in_sizes, int n_in,
                              void* d_out, int out_size, void* d_ws, size_t ws_size,
                              hipStream_t stream) {
  const float* x = (const float*)d_in[0];
  const float* key_kernel = (const float*)d_in[1];
  const float* key_bias = (const float*)d_in[2];
  const float* keys_map = (const float*)d_in[3];
  const float* kernels = (const float*)d_in[4];
  const float* biases = (const float*)d_in[5];
  float* out = (float*)d_out;

  // ws: xbf 8MB | kbf 8MB | wkbf 64KB | simT 512KB
  char* p = (char*)d_ws;
  unsigned short* xbf = (unsigned short*)p;  p += (size_t)B_SZ * D_SZ * 2;
  unsigned short* kbf = (unsigned short*)p;  p += (size_t)M_SZ * U_SZ * D_SZ * 2;
  unsigned short* wkbf = (unsigned short*)p; p += (size_t)K_SZ * D_SZ * 2;
  float* simT = (float*)p;

  prep1<<<dim3(2568), 256, 0, stream>>>(x, key_kernel, kernels, xbf, kbf, wkbf);
  prep2<<<dim3(128), 256, 0, stream>>>(xbf, wkbf, key_bias, keys_map, simT);
  poly_gemm<<<dim3(256), 512, 0, stream>>>(xbf, kbf, simT, biases, out);
}

// Round 8
// 172.154 us; speedup vs baseline: 1.0069x; 1.0069x over previous
//
#include <hip/hip_runtime.h>
#include <hip/hip_bf16.h>
#include <stdint.h>

#define B_SZ 8192
#define D_SZ 512
#define U_SZ 512
#define M_SZ 16
#define K_SZ 64

typedef short bf16x8 __attribute__((ext_vector_type(8)));
typedef float f32x4 __attribute__((ext_vector_type(4)));

__device__ __forceinline__ unsigned short f2bf(float f) {
  union { float f; unsigned u; } v; v.f = f;
  unsigned r = v.u + 0x7fffu + ((v.u >> 16) & 1u);
  return (unsigned short)(r >> 16);
}

// =====================================================================
// prep1: role-split single launch. ALL outputs are fragment-linear bf16.
//  [0,2048):    kernels [M][D][U] f32 -> kbf [m][ut][kt][j][h][lane][8]
//  [2048,2056): key_kernel [D][K]     -> wkbf [kt][j][h][lane][8]
//  [2056,2568): x [B][D]              -> xbf [bt][kt][i][h][lane][8]
// =====================================================================
__global__ __launch_bounds__(256) void prep1(
    const float* __restrict__ x, const float* __restrict__ key_kernel,
    const float* __restrict__ kernels, unsigned short* __restrict__ xbf,
    unsigned short* __restrict__ kbf, unsigned short* __restrict__ wkbf) {
  __shared__ float tf[32][65];
  __shared__ unsigned short sx[16][520];
  int bid = blockIdx.x;
  int t = threadIdx.x;

  if (bid < 2048) {
    // ---- role T: kernels -> kbf (frag-linear B operand) ----
    int m = bid >> 7;
    int rem = bid & 127;
    int a = (rem >> 3) & 15;  // d-tile (32 d's)
    int ut = rem & 7;         // u-tile (64 u's)
    int d0 = a * 32, u0 = ut * 64;
    {
      int dr = t >> 4, uc = t & 15;
      const float* src = kernels + ((size_t)m * D_SZ + d0 + dr) * U_SZ + u0 + uc * 4;
      float4 aa = *(const float4*)src;
      float4 bb = *(const float4*)(src + (size_t)16 * U_SZ);
      tf[dr][uc * 4 + 0] = aa.x; tf[dr][uc * 4 + 1] = aa.y;
      tf[dr][uc * 4 + 2] = aa.z; tf[dr][uc * 4 + 3] = aa.w;
      tf[dr + 16][uc * 4 + 0] = bb.x; tf[dr + 16][uc * 4 + 1] = bb.y;
      tf[dr + 16][uc * 4 + 2] = bb.z; tf[dr + 16][uc * 4 + 3] = bb.w;
    }
    __syncthreads();
    {
      int j = t >> 6;            // frag col-block 0..3 (== wave id)
      int lp = t & 63;           // frag lane 0..63
      int dc = lp >> 4, lane16 = lp & 15;
      int kt = a >> 1, h = a & 1;
      int ur = j * 16 + lane16;  // u-row 0..63
      unsigned short* dst = kbf +
          (((((size_t)m * 8 + ut) * 8 + kt) * 4 + j) * 2 + h) * 512 +
          (size_t)lp * 8;
      ushort4 lo, hi;
      lo.x = f2bf(tf[dc * 8 + 0][ur]); lo.y = f2bf(tf[dc * 8 + 1][ur]);
      lo.z = f2bf(tf[dc * 8 + 2][ur]); lo.w = f2bf(tf[dc * 8 + 3][ur]);
      hi.x = f2bf(tf[dc * 8 + 4][ur]); hi.y = f2bf(tf[dc * 8 + 5][ur]);
      hi.z = f2bf(tf[dc * 8 + 6][ur]); hi.w = f2bf(tf[dc * 8 + 7][ur]);
      *(ushort4*)dst = lo;
      *(ushort4*)(dst + 4) = hi;
    }
    return;
  }

  if (bid < 2056) {
    // ---- role W: key_kernel -> wkbf ----
    int kt = bid - 2048;
#pragma unroll
    for (int rep = 0; rep < 2; ++rep) {
      int c = rep * 256 + t;
      int j = c >> 7, h = (c >> 6) & 1, quad = (c >> 4) & 3, ln = c & 15;
      int dd = kt * 64 + h * 32 + quad * 8;
      int u = j * 16 + ln;
      unsigned short v[8];
#pragma unroll
      for (int e = 0; e < 8; ++e)
        v[e] = f2bf(key_kernel[(size_t)(dd + e) * K_SZ + u]);
      unsigned short* dst =
          wkbf + ((size_t)((kt * 4 + j) * 2 + h) * 64 + quad * 16 + ln) * 8;
#pragma unroll
      for (int e = 0; e < 8; ++e) dst[e] = v[e];
    }
    return;
  }

  // ---- role X (v2): x -> xbf via LDS transpose, coalesced reads ----
  {
    int xb0 = bid - 2056;            // 0..511, 16 rows each
    int btx = xb0 >> 3, i = xb0 & 7;
    int b0 = xb0 * 16;
#pragma unroll
    for (int rep = 0; rep < 8; ++rep) {
      int idx = rep * 256 + t;       // 0..2047
      int row = idx >> 7;            // 0..15
      int c4 = (idx & 127) * 4;      // 0..508
      float4 v = *(const float4*)(x + (size_t)(b0 + row) * D_SZ + c4);
      ushort4 o;
      o.x = f2bf(v.x); o.y = f2bf(v.y); o.z = f2bf(v.z); o.w = f2bf(v.w);
      *(ushort4*)(&sx[row][c4]) = o;
    }
    __syncthreads();
    int w = t >> 6, l = t & 63;
    int ln = l & 15, quad = l >> 4;
#pragma unroll
    for (int rep = 0; rep < 4; ++rep) {
      int c = w * 4 + rep;           // chunk 0..15 = (kt,h)
      int kt = c >> 1, h = c & 1;
      const unsigned short* srcp = &sx[ln][kt * 64 + h * 32 + quad * 8];
      ushort4 lo = *(const ushort4*)(srcp);
      ushort4 hi = *(const ushort4*)(srcp + 4);
      unsigned short* dst =
          xbf + ((((size_t)btx * 8 + kt) * 8 + i) * 2 + h) * 512 + (size_t)l * 8;
      *(ushort4*)dst = lo;
      *(ushort4*)(dst + 4) = hi;
    }
  }
}

// =====================================================================
// prep2: keyv = xb @ Wk + bias (MFMA, frags direct from global), then sim.
// =====================================================================
__global__ __launch_bounds__(256) void prep2(
    const unsigned short* __restrict__ xbf, const unsigned short* __restrict__ wkbf,
    const float* __restrict__ key_bias, const float* __restrict__ keys_map,
    float* __restrict__ simT) {
  __shared__ float kv[64][68];
  __shared__ float sKM[16][64];
  int t = threadIdx.x, w = t >> 6, l = t & 63;
  int blk = blockIdx.x;
  int b0 = blk * 64, bt = blk >> 1, ibase = (blk & 1) * 4;
  int lane16 = l & 15, quad = l >> 4;

  ((float4*)sKM)[t] = ((const float4*)keys_map)[t];

  f32x4 acc[4];
#pragma unroll
  for (int j = 0; j < 4; ++j) acc[j] = (f32x4){0.f, 0.f, 0.f, 0.f};

  for (int kt = 0; kt < 8; ++kt) {
    bf16x8 af[2];
#pragma unroll
    for (int h = 0; h < 2; ++h)
      af[h] = *(const bf16x8*)(xbf +
                               ((((size_t)bt * 8 + kt) * 8 + ibase + w) * 2 + h) * 512 +
                               (size_t)l * 8);
#pragma unroll
    for (int j = 0; j < 4; ++j) {
      bf16x8 b0f = *(const bf16x8*)(wkbf + ((size_t)((kt * 4 + j) * 2 + 0) * 64 + l) * 8);
      bf16x8 b1f = *(const bf16x8*)(wkbf + ((size_t)((kt * 4 + j) * 2 + 1) * 64 + l) * 8);
      acc[j] = __builtin_amdgcn_mfma_f32_16x16x32_bf16(af[0], b0f, acc[j], 0, 0, 0);
      acc[j] = __builtin_amdgcn_mfma_f32_16x16x32_bf16(af[1], b1f, acc[j], 0, 0, 0);
    }
  }
#pragma unroll
  for (int j = 0; j < 4; ++j) {
    float bc = key_bias[j * 16 + lane16];
#pragma unroll
    for (int r = 0; r < 4; ++r)
      kv[w * 16 + quad * 4 + r][j * 16 + lane16] = acc[j][r] + bc;
  }
  __syncthreads();

  int row = t >> 2, mg = (t & 3) * 4;
  float d2[4] = {0.f, 0.f, 0.f, 0.f};
#pragma unroll 8
  for (int k = 0; k < 64; ++k) {
    float kvv = kv[row][k];
#pragma unroll
    for (int q = 0; q < 4; ++q) {
      float df = kvv - sKM[mg + q][k];
      d2[q] += df * df;
    }
  }
#pragma unroll
  for (int q = 0; q < 4; ++q)
    simT[(size_t)(mg + q) * B_SZ + b0 + row] = 1.0f / (sqrtf(d2[q]) + 1.0f);
}

// =====================================================================
// poly_gemm v9: out[b,u] = (1/16) sum_m sim[b,m]*(x@kernels_m + biases_m)
//
// ROUND-8: R7's i=4 mode-split structure was right but SPILLED: the
// empirical launch-bounds rule for 512-thread blocks on this compiler
// is VGPR cap = 256/arg ((512,4)->64 in R1, (512,2)->128 in R7, both
// with massive scratch traffic). This version: __launch_bounds__(512,1)
// -> cap 256. Structure needs ~190 live VGPRs (facc 64 + afc/afn 64 +
// transients) -> fits, and <=256 VGPR still allows 2 waves/SIMD.
// Everything else identical to R7:
//  - 256 blocks (32 bt x 8 ut XCD-pinned), 512 thr = 8 waves =
//    4 row-groups (rg, 64 rows, facc[4][4]) x 2 mode-halves (half).
//  - LDS-read duty = 1024B/MFMA / i; i=4 -> ~20us (was 41 at R6's i=2).
//  - ring: 4 slots x 2 halves x 8KB = 64KB; lookahead 2; one s_barrier
//    per iter; counted vmcnt ledger (verified case-by-case):
//      mi<3 && kt<7 -> vmcnt(12)  [8 af loads ride in the window]
//      else         -> vmcnt(4)   [never 0 in-loop]
//  - epilogue: drain + mode-half combine via sRed overlay.
// =====================================================================
#define GLL(src_, dst_)                                                        \
  __builtin_amdgcn_global_load_lds(                                            \
      (const __attribute__((address_space(1))) unsigned int*)(src_),           \
      (__attribute__((address_space(3))) unsigned int*)(dst_), 16, 0, 0)

#define STAGE(mi_, kt_, slot_)                                                 \
  {                                                                            \
    const unsigned short* _src = kbf_l +                                       \
        (((size_t)((w & 1) * 8 + (mi_)) * 8 + ut) * 8 + (kt_)) * 4096 +        \
        (w >> 1) * 1024;                                                       \
    unsigned short* _dst =                                                     \
        Bbuf + ((slot_) * 2 + (w & 1)) * 4096 + (w >> 1) * 1024;               \
    GLL(_src, _dst);                                                           \
    GLL(_src + 512, _dst + 512);                                               \
  }

#define LOAD_AF(dst_, kt_)                                                     \
  _Pragma("unroll") for (int ii = 0; ii < 4; ++ii)                             \
      _Pragma("unroll") for (int h = 0; h < 2; ++h) {                          \
    int g_ = bt * 16 + rg * 4 + ii;                                            \
    dst_[ii][h] = *(const bf16x8*)(                                            \
        xbf + ((((size_t)(g_ >> 3) * 8 + (kt_)) * 8 + (g_ & 7)) * 2 + h) *     \
                  512 +                                                        \
              (size_t)l * 8);                                                  \
  }

__global__ __launch_bounds__(512, 1) void poly_gemm(
    const unsigned short* __restrict__ xbf,  // A frag-linear
    const unsigned short* __restrict__ kbf,  // B frag-linear
    const float* __restrict__ simT,          // [M][B]
    const float* __restrict__ biases,        // [M][U] f32
    float* __restrict__ out) {               // [B][U]
  // LDS: [0,64K) 4slot x 2half x 8KB | [64K,80K) sSim[16][256] |
  // [80K,84K) sBias[16][64]. Epilogue overlays sRed (256x68 f32).
  __shared__ __align__(16) char smem[86016];

  int t = threadIdx.x, w = t >> 6, l = t & 63;
  int bid = blockIdx.x;
  int ut = bid & 7, bt = bid >> 3;  // ut: XCD-pinned kbf slice
  int b0 = bt * 256, u0 = ut * 64;
  int rg = w >> 1, half = w & 1;
  int lane16 = l & 15, quad = l >> 4;

  unsigned short* Bbuf = (unsigned short*)smem;
  float* sSim = (float*)(smem + 65536);
  float* sBias = (float*)(smem + 81920);

  // ---- stage sim [16][256] and bias [16][64] once (512 threads) ----
  {
    int m = t >> 5, c = (t & 31) * 8;
    const float* src = simT + (size_t)m * B_SZ + b0 + c;
    float4* dst = (float4*)(sSim + m * 256 + c);
    dst[0] = ((const float4*)src)[0];
    dst[1] = ((const float4*)src)[1];
    int bi = t * 2;  // 0..1022
    *(float2*)(sBias + bi) =
        *(const float2*)(biases + (size_t)(bi >> 6) * U_SZ + u0 + (bi & 63));
  }

  const unsigned short* kbf_l = kbf + (size_t)l * 8;

  bf16x8 afc[4][2], afn[4][2];

  // prologue: stage slices s=0,1 (both halves), load af(kt0), drain.
  STAGE(0, 0, 0);
  STAGE(1, 0, 1);
  LOAD_AF(afc, 0);
  asm volatile("s_waitcnt vmcnt(0)" ::: "memory");
  __syncthreads();

  f32x4 facc[4][4];
#pragma unroll
  for (int i = 0; i < 4; ++i)
#pragma unroll
    for (int j = 0; j < 4; ++j) facc[i][j] = (f32x4){0.f, 0.f, 0.f, 0.f};

#pragma unroll 1
  for (int kt = 0; kt < 8; ++kt) {
#pragma unroll
    for (int mi = 0; mi < 8; ++mi) {
      const int s = kt * 8 + mi;
      const int mode = half * 8 + mi;
      // stage slice s+2 for this wave's half
      {
        int mi2 = (mi + 2) & 7;
        int kt2 = (mi >= 6) ? ((kt + 1) & 7) : kt;
        STAGE(mi2, kt2, (s + 2) & 3);
      }
      if (mi == 0 && kt < 7) { LOAD_AF(afn, kt + 1); }
      // counted waits per the ledger (never 0 in-loop)
      if (mi < 3 && kt < 7)
        asm volatile("s_waitcnt vmcnt(12)" ::: "memory");
      else
        asm volatile("s_waitcnt vmcnt(4)" ::: "memory");
      asm volatile("s_barrier" ::: "memory");

      const unsigned short* lb = Bbuf + ((s & 3) * 2 + half) * 4096;
      bf16x8 bfr[4][2];
#pragma unroll
      for (int j = 0; j < 4; ++j)
#pragma unroll
        for (int h = 0; h < 2; ++h)
          bfr[j][h] = *(const bf16x8*)(lb + (j * 2 + h) * 512 + (size_t)l * 8);

      f32x4 sv[4];
#pragma unroll
      for (int i = 0; i < 4; ++i)
        sv[i] = *(const f32x4*)(sSim + mode * 256 + rg * 64 + i * 16 +
                                quad * 4);

#pragma unroll
      for (int i = 0; i < 4; ++i)
#pragma unroll
        for (int j = 0; j < 4; ++j) {
          f32x4 p = __builtin_amdgcn_mfma_f32_16x16x32_bf16(
              afc[i][0], bfr[j][0], (f32x4){0.f, 0.f, 0.f, 0.f}, 0, 0, 0);
          p = __builtin_amdgcn_mfma_f32_16x16x32_bf16(afc[i][1], bfr[j][1], p,
                                                      0, 0, 0);
#pragma unroll
          for (int r = 0; r < 4; ++r) facc[i][j][r] += sv[i][r] * p[r];
        }

      if (kt == 0) {  // sim-weighted bias, once per mode
        float bbv[4];
#pragma unroll
        for (int j = 0; j < 4; ++j)
          bbv[j] = sBias[mode * 64 + j * 16 + lane16];
#pragma unroll
        for (int i = 0; i < 4; ++i)
#pragma unroll
          for (int j = 0; j < 4; ++j)
#pragma unroll
            for (int r = 0; r < 4; ++r) facc[i][j][r] += sv[i][r] * bbv[j];
      }
    }
    if (kt < 7) {
#pragma unroll
      for (int ii = 0; ii < 4; ++ii)
#pragma unroll
        for (int h = 0; h < 2; ++h) afc[ii][h] = afn[ii][h];
    }
  }

  // epilogue: drain wrap-stage DMA, then mode-half combine via sRed.
  asm volatile("s_waitcnt vmcnt(0)" ::: "memory");
  __syncthreads();
  float* sRed = (float*)smem;  // [256][68] overlay on Bbuf+sSim
  if (half == 1) {
#pragma unroll
    for (int i = 0; i < 4; ++i)
#pragma unroll
      for (int r = 0; r < 4; ++r)
#pragma unroll
        for (int j = 0; j < 4; ++j)
          sRed[(rg * 64 + i * 16 + quad * 4 + r) * 68 + j * 16 + lane16] =
              facc[i][j][r];
  }
  __syncthreads();
  if (half == 0) {
#pragma unroll
    for (int i = 0; i < 4; ++i)
#pragma unroll
      for (int r = 0; r < 4; ++r) {
        int row = b0 + rg * 64 + i * 16 + quad * 4 + r;
        float* orow = out + (size_t)row * U_SZ + u0;
#pragma unroll
        for (int j = 0; j < 4; ++j)
          orow[j * 16 + lane16] =
              (facc[i][j][r] +
               sRed[(rg * 64 + i * 16 + quad * 4 + r) * 68 + j * 16 + lane16]) *
              0.0625f;
      }
  }
}

extern "C" void kernel_launch(void* const* d_in, const int* in_sizes, int n_in,
                              void* d_out, int out_size, void* d_ws, size_t ws_size,
                              hipStream_t stream) {
  const float* x = (const float*)d_in[0];
  const float* key_kernel = (const float*)d_in[1];
  const float* key_bias = (const float*)d_in[2];
  const float* keys_map = (const float*)d_in[3];
  const float* kernels = (const float*)d_in[4];
  const float* biases = (const float*)d_in[5];
  float* out = (float*)d_out;

  // ws: xbf 8MB | kbf 8MB | wkbf 64KB | simT 512KB
  char* p = (char*)d_ws;
  unsigned short* xbf = (unsigned short*)p;  p += (size_t)B_SZ * D_SZ * 2;
  unsigned short* kbf = (unsigned short*)p;  p += (size_t)M_SZ * U_SZ * D_SZ * 2;
  unsigned short* wkbf = (unsigned short*)p; p += (size_t)K_SZ * D_SZ * 2;
  float* simT = (float*)p;

  prep1<<<dim3(2568), 256, 0, stream>>>(x, key_kernel, kernels, xbf, kbf, wkbf);
  prep2<<<dim3(128), 256, 0, stream>>>(xbf, wkbf, key_bias, keys_map, simT);
  poly_gemm<<<dim3(256), 512, 0, stream>>>(xbf, kbf, simT, biases, out);
}

// Round 9
// 169.910 us; speedup vs baseline: 1.0202x; 1.0132x over previous
//
#include <hip/hip_runtime.h>
#include <hip/hip_bf16.h>
#include <stdint.h>

#define B_SZ 8192
#define D_SZ 512
#define U_SZ 512
#define M_SZ 16
#define K_SZ 64

typedef short bf16x8 __attribute__((ext_vector_type(8)));
typedef float f32x4 __attribute__((ext_vector_type(4)));

__device__ __forceinline__ unsigned short f2bf(float f) {
  union { float f; unsigned u; } v; v.f = f;
  unsigned r = v.u + 0x7fffu + ((v.u >> 16) & 1u);
  return (unsigned short)(r >> 16);
}

// =====================================================================
// prep1: role-split single launch. ALL outputs are fragment-linear bf16.
//  [0,2048):    kernels [M][D][U] f32 -> kbf [m][ut][kt][j][h][lane][8]
//  [2048,2056): key_kernel [D][K]     -> wkbf [kt][j][h][lane][8]
//  [2056,2568): x [B][D]              -> xbf [bt][kt][i][h][lane][8]
// =====================================================================
__global__ __launch_bounds__(256) void prep1(
    const float* __restrict__ x, const float* __restrict__ key_kernel,
    const float* __restrict__ kernels, unsigned short* __restrict__ xbf,
    unsigned short* __restrict__ kbf, unsigned short* __restrict__ wkbf) {
  __shared__ float tf[32][65];
  __shared__ unsigned short sx[16][520];
  int bid = blockIdx.x;
  int t = threadIdx.x;

  if (bid < 2048) {
    // ---- role T: kernels -> kbf (frag-linear B operand) ----
    int m = bid >> 7;
    int rem = bid & 127;
    int a = (rem >> 3) & 15;  // d-tile (32 d's)
    int ut = rem & 7;         // u-tile (64 u's)
    int d0 = a * 32, u0 = ut * 64;
    {
      int dr = t >> 4, uc = t & 15;
      const float* src = kernels + ((size_t)m * D_SZ + d0 + dr) * U_SZ + u0 + uc * 4;
      float4 aa = *(const float4*)src;
      float4 bb = *(const float4*)(src + (size_t)16 * U_SZ);
      tf[dr][uc * 4 + 0] = aa.x; tf[dr][uc * 4 + 1] = aa.y;
      tf[dr][uc * 4 + 2] = aa.z; tf[dr][uc * 4 + 3] = aa.w;
      tf[dr + 16][uc * 4 + 0] = bb.x; tf[dr + 16][uc * 4 + 1] = bb.y;
      tf[dr + 16][uc * 4 + 2] = bb.z; tf[dr + 16][uc * 4 + 3] = bb.w;
    }
    __syncthreads();
    {
      int j = t >> 6;            // frag col-block 0..3 (== wave id)
      int lp = t & 63;           // frag lane 0..63
      int dc = lp >> 4, lane16 = lp & 15;
      int kt = a >> 1, h = a & 1;
      int ur = j * 16 + lane16;  // u-row 0..63
      unsigned short* dst = kbf +
          (((((size_t)m * 8 + ut) * 8 + kt) * 4 + j) * 2 + h) * 512 +
          (size_t)lp * 8;
      ushort4 lo, hi;
      lo.x = f2bf(tf[dc * 8 + 0][ur]); lo.y = f2bf(tf[dc * 8 + 1][ur]);
      lo.z = f2bf(tf[dc * 8 + 2][ur]); lo.w = f2bf(tf[dc * 8 + 3][ur]);
      hi.x = f2bf(tf[dc * 8 + 4][ur]); hi.y = f2bf(tf[dc * 8 + 5][ur]);
      hi.z = f2bf(tf[dc * 8 + 6][ur]); hi.w = f2bf(tf[dc * 8 + 7][ur]);
      *(ushort4*)dst = lo;
      *(ushort4*)(dst + 4) = hi;
    }
    return;
  }

  if (bid < 2056) {
    // ---- role W: key_kernel -> wkbf ----
    int kt = bid - 2048;
#pragma unroll
    for (int rep = 0; rep < 2; ++rep) {
      int c = rep * 256 + t;
      int j = c >> 7, h = (c >> 6) & 1, quad = (c >> 4) & 3, ln = c & 15;
      int dd = kt * 64 + h * 32 + quad * 8;
      int u = j * 16 + ln;
      unsigned short v[8];
#pragma unroll
      for (int e = 0; e < 8; ++e)
        v[e] = f2bf(key_kernel[(size_t)(dd + e) * K_SZ + u]);
      unsigned short* dst =
          wkbf + ((size_t)((kt * 4 + j) * 2 + h) * 64 + quad * 16 + ln) * 8;
#pragma unroll
      for (int e = 0; e < 8; ++e) dst[e] = v[e];
    }
    return;
  }

  // ---- role X (v2): x -> xbf via LDS transpose, coalesced reads ----
  {
    int xb0 = bid - 2056;            // 0..511, 16 rows each
    int btx = xb0 >> 3, i = xb0 & 7;
    int b0 = xb0 * 16;
#pragma unroll
    for (int rep = 0; rep < 8; ++rep) {
      int idx = rep * 256 + t;       // 0..2047
      int row = idx >> 7;            // 0..15
      int c4 = (idx & 127) * 4;      // 0..508
      float4 v = *(const float4*)(x + (size_t)(b0 + row) * D_SZ + c4);
      ushort4 o;
      o.x = f2bf(v.x); o.y = f2bf(v.y); o.z = f2bf(v.z); o.w = f2bf(v.w);
      *(ushort4*)(&sx[row][c4]) = o;
    }
    __syncthreads();
    int w = t >> 6, l = t & 63;
    int ln = l & 15, quad = l >> 4;
#pragma unroll
    for (int rep = 0; rep < 4; ++rep) {
      int c = w * 4 + rep;           // chunk 0..15 = (kt,h)
      int kt = c >> 1, h = c & 1;
      const unsigned short* srcp = &sx[ln][kt * 64 + h * 32 + quad * 8];
      ushort4 lo = *(const ushort4*)(srcp);
      ushort4 hi = *(const ushort4*)(srcp + 4);
      unsigned short* dst =
          xbf + ((((size_t)btx * 8 + kt) * 8 + i) * 2 + h) * 512 + (size_t)l * 8;
      *(ushort4*)dst = lo;
      *(ushort4*)(dst + 4) = hi;
    }
  }
}

// =====================================================================
// prep2: keyv = xb @ Wk + bias (MFMA, frags direct from global), then sim.
// =====================================================================
__global__ __launch_bounds__(256) void prep2(
    const unsigned short* __restrict__ xbf, const unsigned short* __restrict__ wkbf,
    const float* __restrict__ key_bias, const float* __restrict__ keys_map,
    float* __restrict__ simT) {
  __shared__ float kv[64][68];
  __shared__ float sKM[16][64];
  int t = threadIdx.x, w = t >> 6, l = t & 63;
  int blk = blockIdx.x;
  int b0 = blk * 64, bt = blk >> 1, ibase = (blk & 1) * 4;
  int lane16 = l & 15, quad = l >> 4;

  ((float4*)sKM)[t] = ((const float4*)keys_map)[t];

  f32x4 acc[4];
#pragma unroll
  for (int j = 0; j < 4; ++j) acc[j] = (f32x4){0.f, 0.f, 0.f, 0.f};

  for (int kt = 0; kt < 8; ++kt) {
    bf16x8 af[2];
#pragma unroll
    for (int h = 0; h < 2; ++h)
      af[h] = *(const bf16x8*)(xbf +
                               ((((size_t)bt * 8 + kt) * 8 + ibase + w) * 2 + h) * 512 +
                               (size_t)l * 8);
#pragma unroll
    for (int j = 0; j < 4; ++j) {
      bf16x8 b0f = *(const bf16x8*)(wkbf + ((size_t)((kt * 4 + j) * 2 + 0) * 64 + l) * 8);
      bf16x8 b1f = *(const bf16x8*)(wkbf + ((size_t)((kt * 4 + j) * 2 + 1) * 64 + l) * 8);
      acc[j] = __builtin_amdgcn_mfma_f32_16x16x32_bf16(af[0], b0f, acc[j], 0, 0, 0);
      acc[j] = __builtin_amdgcn_mfma_f32_16x16x32_bf16(af[1], b1f, acc[j], 0, 0, 0);
    }
  }
#pragma unroll
  for (int j = 0; j < 4; ++j) {
    float bc = key_bias[j * 16 + lane16];
#pragma unroll
    for (int r = 0; r < 4; ++r)
      kv[w * 16 + quad * 4 + r][j * 16 + lane16] = acc[j][r] + bc;
  }
  __syncthreads();

  int row = t >> 2, mg = (t & 3) * 4;
  float d2[4] = {0.f, 0.f, 0.f, 0.f};
#pragma unroll 8
  for (int k = 0; k < 64; ++k) {
    float kvv = kv[row][k];
#pragma unroll
    for (int q = 0; q < 4; ++q) {
      float df = kvv - sKM[mg + q][k];
      d2[q] += df * df;
    }
  }
#pragma unroll
  for (int q = 0; q < 4; ++q)
    simT[(size_t)(mg + q) * B_SZ + b0 + row] = 1.0f / (sqrtf(d2[q]) + 1.0f);
}

// =====================================================================
// poly_gemm v10: out[b,u] = (1/16) sum_m sim[b,m]*(x@kernels_m+biases_m)
//
// ROUND-9: the i=4 structure twice failed to EXECUTE (not failed on
// merit): 512-thread blocks cap at <=128 VGPR on this compiler no
// matter the launch-bounds arg ((512,4)->64, (512,2)->128, (512,1)->128,
// all with scratch spill). Re-hosted on 256-thread blocks where (256,2)
// demonstrably lets the allocator run free up to 256 (R0: 108 natural).
//  - 512 blocks = 64 bt (128 rows) x 8 ut (XCD-pinned via bid&7).
//  - 256 thr = 4 waves = 2 row-groups (rg: 64 rows, facc[4][4], i=4)
//    x 2 mode-halves (half). ~180 live VGPRs -> fits the 256 cap.
//  - 2 blocks/CU (LDS 76KB x2 = 152 <= 160KB) -> 8 waves/CU =
//    2 waves/SIMD via CO-RESIDENT BLOCKS (independent barriers).
//  - ring 4 slots x 2 halves x 8KB = 64KB; lookahead 2; per wave
//    4x 1KB global_load_lds per iter (half-slice split over 2 rg waves).
//  - vmcnt ledger (4 GLL/iter/wave; af=8 loads issued at mi==0,kt<7
//    AFTER that iter's stage): newer-than-stage(s) =
//      mi<3 && kt<7 -> 16 ;  else -> 8.   Never 0 in-loop.
//    af drain at the kt-boundary copy is compiler-inserted (it tracks
//    the global_load_lds builtin in its own vmcnt bookkeeping).
//  - epilogue: drain + mode-half combine via sRed[128][68] overlay.
// =====================================================================
#define GLL(src_, dst_)                                                        \
  __builtin_amdgcn_global_load_lds(                                            \
      (const __attribute__((address_space(1))) unsigned int*)(src_),           \
      (__attribute__((address_space(3))) unsigned int*)(dst_), 16, 0, 0)

#define STAGE(mi_, kt_, slot_)                                                 \
  {                                                                            \
    const unsigned short* _src = kbf_l +                                       \
        (((size_t)(half * 8 + (mi_)) * 8 + ut) * 8 + (kt_)) * 4096 +           \
        rg * 2048;                                                             \
    unsigned short* _dst =                                                     \
        Bbuf + ((slot_) * 2 + half) * 4096 + rg * 2048;                        \
    GLL(_src, _dst);                                                           \
    GLL(_src + 512, _dst + 512);                                               \
    GLL(_src + 1024, _dst + 1024);                                             \
    GLL(_src + 1536, _dst + 1536);                                             \
  }

#define LOAD_AF(dst_, kt_)                                                     \
  _Pragma("unroll") for (int ii = 0; ii < 4; ++ii)                             \
      _Pragma("unroll") for (int h = 0; h < 2; ++h) {                          \
    int g_ = btv * 8 + rg * 4 + ii;                                            \
    dst_[ii][h] = *(const bf16x8*)(                                            \
        xbf + ((((size_t)(g_ >> 3) * 8 + (kt_)) * 8 + (g_ & 7)) * 2 + h) *     \
                  512 +                                                        \
              (size_t)l * 8);                                                  \
  }

__global__ __launch_bounds__(256, 2) void poly_gemm(
    const unsigned short* __restrict__ xbf,  // A frag-linear
    const unsigned short* __restrict__ kbf,  // B frag-linear
    const float* __restrict__ simT,          // [M][B]
    const float* __restrict__ biases,        // [M][U] f32
    float* __restrict__ out) {               // [B][U]
  // LDS: [0,64K) 4slot x 2half x 8KB | [64K,72K) sSim[16][128] |
  // [72K,76K) sBias[16][64]. Epilogue overlays sRed[128][68] on ring.
  __shared__ __align__(16) char smem[77824];

  int t = threadIdx.x, w = t >> 6, l = t & 63;
  int bid = blockIdx.x;
  int ut = bid & 7, btv = bid >> 3;  // ut: XCD-pinned kbf slice
  int b0 = btv * 128, u0 = ut * 64;
  int rg = w >> 1, half = w & 1;
  int lane16 = l & 15, quad = l >> 4;

  unsigned short* Bbuf = (unsigned short*)smem;
  float* sSim = (float*)(smem + 65536);
  float* sBias = (float*)(smem + 73728);

  // ---- stage sim [16][128] and bias [16][64] once (256 threads) ----
  {
    int m = t >> 4, c = (t & 15) * 8;
    const float* src = simT + (size_t)m * B_SZ + b0 + c;
    float4* dst = (float4*)(sSim + m * 128 + c);
    dst[0] = ((const float4*)src)[0];
    dst[1] = ((const float4*)src)[1];
    int bi = t * 4;  // 0..1020
    *(float4*)(sBias + bi) =
        *(const float4*)(biases + (size_t)(bi >> 6) * U_SZ + u0 + (bi & 63));
  }

  const unsigned short* kbf_l = kbf + (size_t)l * 8;

  bf16x8 afc[4][2], afn[4][2];

  // prologue: stage slices s=0,1 (both halves), load af(kt0), drain.
  STAGE(0, 0, 0);
  STAGE(1, 0, 1);
  LOAD_AF(afc, 0);
  asm volatile("s_waitcnt vmcnt(0)" ::: "memory");
  __syncthreads();

  f32x4 facc[4][4];
#pragma unroll
  for (int i = 0; i < 4; ++i)
#pragma unroll
    for (int j = 0; j < 4; ++j) facc[i][j] = (f32x4){0.f, 0.f, 0.f, 0.f};

#pragma unroll 1
  for (int kt = 0; kt < 8; ++kt) {
#pragma unroll
    for (int mi = 0; mi < 8; ++mi) {
      const int s = kt * 8 + mi;
      const int mode = half * 8 + mi;
      // stage slice s+2 for this wave's half
      {
        int mi2 = (mi + 2) & 7;
        int kt2 = (mi >= 6) ? ((kt + 1) & 7) : kt;
        STAGE(mi2, kt2, (s + 2) & 3);
      }
      if (mi == 0 && kt < 7) { LOAD_AF(afn, kt + 1); }
      // counted waits per the ledger (never 0 in-loop)
      if (mi < 3 && kt < 7)
        asm volatile("s_waitcnt vmcnt(16)" ::: "memory");
      else
        asm volatile("s_waitcnt vmcnt(8)" ::: "memory");
      asm volatile("s_barrier" ::: "memory");

      const unsigned short* lb = Bbuf + ((s & 3) * 2 + half) * 4096;
      bf16x8 bfr[4][2];
#pragma unroll
      for (int j = 0; j < 4; ++j)
#pragma unroll
        for (int h = 0; h < 2; ++h)
          bfr[j][h] = *(const bf16x8*)(lb + (j * 2 + h) * 512 + (size_t)l * 8);

      f32x4 sv[4];
#pragma unroll
      for (int i = 0; i < 4; ++i)
        sv[i] = *(const f32x4*)(sSim + mode * 128 + rg * 64 + i * 16 +
                                quad * 4);

#pragma unroll
      for (int i = 0; i < 4; ++i)
#pragma unroll
        for (int j = 0; j < 4; ++j) {
          f32x4 p = __builtin_amdgcn_mfma_f32_16x16x32_bf16(
              afc[i][0], bfr[j][0], (f32x4){0.f, 0.f, 0.f, 0.f}, 0, 0, 0);
          p = __builtin_amdgcn_mfma_f32_16x16x32_bf16(afc[i][1], bfr[j][1], p,
                                                      0, 0, 0);
#pragma unroll
          for (int r = 0; r < 4; ++r) facc[i][j][r] += sv[i][r] * p[r];
        }

      if (kt == 0) {  // sim-weighted bias, once per mode
        float bbv[4];
#pragma unroll
        for (int j = 0; j < 4; ++j)
          bbv[j] = sBias[mode * 64 + j * 16 + lane16];
#pragma unroll
        for (int i = 0; i < 4; ++i)
#pragma unroll
          for (int j = 0; j < 4; ++j)
#pragma unroll
            for (int r = 0; r < 4; ++r) facc[i][j][r] += sv[i][r] * bbv[j];
      }
    }
    if (kt < 7) {
#pragma unroll
      for (int ii = 0; ii < 4; ++ii)
#pragma unroll
        for (int h = 0; h < 2; ++h) afc[ii][h] = afn[ii][h];
    }
  }

  // epilogue: drain wrap-stage DMA, then mode-half combine via sRed.
  asm volatile("s_waitcnt vmcnt(0)" ::: "memory");
  __syncthreads();
  float* sRed = (float*)smem;  // [128][68] overlay on ring
  if (half == 1) {
#pragma unroll
    for (int i = 0; i < 4; ++i)
#pragma unroll
      for (int r = 0; r < 4; ++r)
#pragma unroll
        for (int j = 0; j < 4; ++j)
          sRed[(rg * 64 + i * 16 + quad * 4 + r) * 68 + j * 16 + lane16] =
              facc[i][j][r];
  }
  __syncthreads();
  if (half == 0) {
#pragma unroll
    for (int i = 0; i < 4; ++i)
#pragma unroll
      for (int r = 0; r < 4; ++r) {
        int row = b0 + rg * 64 + i * 16 + quad * 4 + r;
        float* orow = out + (size_t)row * U_SZ + u0;
#pragma unroll
        for (int j = 0; j < 4; ++j)
          orow[j * 16 + lane16] =
              (facc[i][j][r] +
               sRed[(rg * 64 + i * 16 + quad * 4 + r) * 68 + j * 16 + lane16]) *
              0.0625f;
      }
  }
}

extern "C" void kernel_launch(void* const* d_in, const int* in_sizes, int n_in,
                              void* d_out, int out_size, void* d_ws, size_t ws_size,
                              hipStream_t stream) {
  const float* x = (const float*)d_in[0];
  const float* key_kernel = (const float*)d_in[1];
  const float* key_bias = (const float*)d_in[2];
  const float* keys_map = (const float*)d_in[3];
  const float* kernels = (const float*)d_in[4];
  const float* biases = (const float*)d_in[5];
  float* out = (float*)d_out;

  // ws: xbf 8MB | kbf 8MB | wkbf 64KB | simT 512KB
  char* p = (char*)d_ws;
  unsigned short* xbf = (unsigned short*)p;  p += (size_t)B_SZ * D_SZ * 2;
  unsigned short* kbf = (unsigned short*)p;  p += (size_t)M_SZ * U_SZ * D_SZ * 2;
  unsigned short* wkbf = (unsigned short*)p; p += (size_t)K_SZ * D_SZ * 2;
  float* simT = (float*)p;

  prep1<<<dim3(2568), 256, 0, stream>>>(x, key_kernel, kernels, xbf, kbf, wkbf);
  prep2<<<dim3(128), 256, 0, stream>>>(xbf, wkbf, key_bias, keys_map, simT);
  poly_gemm<<<dim3(512), 256, 0, stream>>>(xbf, kbf, simT, biases, out);
}